// Round 18
// baseline (415.271 us; speedup 1.0000x reference)
//
#include <hip/hip_runtime.h>

#define Tlen 512
#define IND 18
#define HD 12
#define L2E 1.44269504088896340736f

typedef float f32x4 __attribute__((ext_vector_type(4)));
typedef float v4f  __attribute__((ext_vector_type(4)));
typedef float v2f  __attribute__((ext_vector_type(2)));
typedef __fp16 fh8 __attribute__((ext_vector_type(8)));
typedef __fp16 fh2 __attribute__((ext_vector_type(2)));
typedef unsigned u32a __attribute__((may_alias));
typedef __fp16  fp16a __attribute__((may_alias));

__device__ __forceinline__ float sigmoid_s(float x) {   // arg pre-scaled by log2e
  return __builtin_amdgcn_rcpf(1.f + __builtin_amdgcn_exp2f(-x));
}
__device__ __forceinline__ float tanh_s(float x) {      // arg pre-scaled by 2*log2e
  return 1.f - 2.f * __builtin_amdgcn_rcpf(1.f + __builtin_amdgcn_exp2f(x));
}
__device__ __forceinline__ fh2 pk(float a, float b) {
  return __builtin_amdgcn_cvt_pkrtz(a, b);
}
__device__ __forceinline__ fh8 mk8(fh2 a, fh2 b, fh2 c, fh2 d) {
  return (fh8){a[0], a[1], b[0], b[1], c[0], c[1], d[0], d[1]};
}
__device__ __forceinline__ f32x4 MFMA(fh8 a, fh8 b, f32x4 c) {
  return __builtin_amdgcn_mfma_f32_16x16x32_f16(a, b, c, 0, 0, 0);
}
__device__ __forceinline__ f32x4 splat(float s) { return (f32x4){s, s, s, s}; }
__device__ __forceinline__ fh2 ldsrd(const unsigned* w, int idx) {
  return __builtin_bit_cast(fh2, ((const u32a*)w)[idx]);
}
__device__ __forceinline__ int expo2(float v) {   // exact log2 of a power of two
  return (int)((__builtin_bit_cast(unsigned, v) >> 23) & 0xFFu) - 127;
}

// MFMA GRU with RUNTIME LAYOUT PROBES: one wave = 16 batches, both layers,
// zero barriers. The MFMA lane-maps (C position map; A-slot/B-slot k pairing)
// are measured at kernel start with probe MFMAs on exact powers of two and
// consumed as data: B-weights packed via keff[] (correct for any bijective
// slot pairing), gate-phase addressing via probed (mrow, ncol) per C-reg.
// A-fragments keep nominal slot->k fill. f16 in, f32 accumulate (= round 16).
extern "C" __global__ void __launch_bounds__(64, 1) gru2_mfma_p(
    const float* __restrict__ x,
    const float* __restrict__ wih0, const float* __restrict__ whh0,
    const float* __restrict__ bih0, const float* __restrict__ bhh0,
    const float* __restrict__ wih1, const float* __restrict__ whh1,
    const float* __restrict__ bih1, const float* __restrict__ bhh1,
    const float* __restrict__ fcw, const float* __restrict__ fcb,
    float* __restrict__ out)
{
  const int L   = threadIdx.x & 63;
  const int n   = L & 15;        // B-col owner / A-row owner (lane&15)
  const int grp = L >> 4;
  const int b0  = blockIdx.x * 16;

  __shared__ unsigned h1w[16 * 6];   // h1 [16 batch][12 dim] f16, rows 24B
  __shared__ unsigned h2w[16 * 6];

  // ================= probe phase =================
  fh8 a_e, a_g, a_m, a_1;
#pragma unroll
  for (int e = 0; e < 8; ++e) {
    a_e[e] = (__fp16)(float)(1 << e);
    a_g[e] = (__fp16)(float)(1 << grp);
    a_m[e] = (__fp16)(float)n;
    a_1[e] = (__fp16)1.0f;
  }
  int keff[8];   // nominal A-slot index paired with MY lane's B-slot E
#pragma unroll
  for (int G = 0; G < 4; ++G) {
#pragma unroll
    for (int E = 0; E < 8; ++E) {
      fh8 bb;
#pragma unroll
      for (int e = 0; e < 8; ++e) bb[e] = (__fp16)((grp == G && e == E) ? 1.0f : 0.0f);
      f32x4 d1 = MFMA(a_e, bb, splat(0.f));   // 2^(e-part of paired A-slot)
      f32x4 d2 = MFMA(a_g, bb, splat(0.f));   // 2^(grp-part)
      if (grp == G) keff[E] = expo2(d2[0]) * 8 + expo2(d1[0]);
    }
  }
  f32x4 dm = MFMA(a_m, a_1, splat(0.f));      // 32 * C-row identity
  f32x4 dn = MFMA(a_1, a_m, splat(0.f));      // 32 * C-col identity
  int mrow[4], ncol[4], wr_idx[4], wrok[4], fcok[4];
  float* outq[4];
#pragma unroll
  for (int i = 0; i < 4; ++i) {
    mrow[i] = (int)(dm[i] * 0.03125f + 0.5f);
    ncol[i] = (int)(dn[i] * 0.03125f + 0.5f);
    wr_idx[i] = mrow[i] * 12 + ncol[i];
    wrok[i] = (ncol[i] < HD);
    fcok[i] = (ncol[i] == 12);
    outq[i] = out + (size_t)(b0 + mrow[i]) * Tlen;
  }

  // ================= weights (B-slot E holds w_nom[keff[E]]) =================
  fh8 w0[4], w1[4];
#pragma unroll
  for (int c = 0; c < 4; ++c) {
#pragma unroll
    for (int E = 0; E < 8; ++E) {
      const int k   = keff[E];
      const int kx  = (k < IND) ? k : 0;
      const int kh0 = (k >= IND && k < IND + HD) ? (k - IND) : 0;
      const int kA  = (k < HD) ? k : 0;
      const int kB  = (k >= HD && k < 2 * HD) ? (k - HD) : 0;
      const bool inx = (k < IND), inh0 = (k >= IND && k < IND + HD);
      const bool inA = (k < HD),  inB  = (k >= HD && k < 2 * HD);
      float wv0 = 0.f, wv1 = 0.f;
      if (n < HD) {
        if (c == 0) {
          wv0 = inx ? wih0[(0*HD+n)*IND + kx] * L2E : (inh0 ? whh0[(0*HD+n)*HD + kh0] * L2E : 0.f);
          wv1 = inA ? wih1[(0*HD+n)*HD + kA] * L2E : (inB ? whh1[(0*HD+n)*HD + kB] * L2E : 0.f);
        } else if (c == 1) {
          wv0 = inx ? wih0[(1*HD+n)*IND + kx] * L2E : (inh0 ? whh0[(1*HD+n)*HD + kh0] * L2E : 0.f);
          wv1 = inA ? wih1[(1*HD+n)*HD + kA] * L2E : (inB ? whh1[(1*HD+n)*HD + kB] * L2E : 0.f);
        } else if (c == 2) {
          wv0 = inx ? wih0[(2*HD+n)*IND + kx] * (2*L2E) : 0.f;
          wv1 = inA ? wih1[(2*HD+n)*HD + kA] * (2*L2E) : 0.f;
        } else {
          wv0 = inh0 ? whh0[(2*HD+n)*HD + kh0] * (2*L2E) : 0.f;
          wv1 = inB  ? whh1[(2*HD+n)*HD + kB] * (2*L2E) : 0.f;
        }
      } else if (n == 12 && c == 0) {
        wv1 = inB ? fcw[kB] : 0.f;    // FC rides col 12 of L1's r-call
      }
      w0[c][E] = (__fp16)wv0;
      w1[c][E] = (__fp16)wv1;
    }
  }
  // ---- per-reg bias C-operands (column = probed ncol[i]) ----
  f32x4 cb00, cb01, cb02, cb03, cb10, cb11, cb12, cb13;
#pragma unroll
  for (int i = 0; i < 4; ++i) {
    const int cc  = ncol[i];
    const int c12 = (cc < HD) ? cc : 0;
    const bool ok = (cc < HD);
    cb00[i] = ok ? (bih0[c12] + bhh0[c12]) * L2E : 0.f;
    cb01[i] = ok ? (bih0[HD + c12] + bhh0[HD + c12]) * L2E : 0.f;
    cb02[i] = ok ? bih0[2*HD + c12] * (2*L2E) : 0.f;
    cb03[i] = ok ? bhh0[2*HD + c12] * (2*L2E) : 0.f;
    cb10[i] = ok ? (bih1[c12] + bhh1[c12]) * L2E : (cc == 12 ? fcb[0] : 0.f);
    cb11[i] = ok ? (bih1[HD + c12] + bhh1[HD + c12]) * L2E : 0.f;
    cb12[i] = ok ? bih1[2*HD + c12] * (2*L2E) : 0.f;
    cb13[i] = ok ? bhh1[2*HD + c12] * (2*L2E) : 0.f;
  }

  // ---- LDS word-index tables for A-fragment reads (row = n = batch) ----
  const int rb = n * 6;
  int i1a, i1b, i1c, i1d, i2a, i2b, i2c, i2d;
  if (grp == 0)      { i1a=rb+0; i1b=rb+1; i1c=rb+2; i1d=rb+3; i2a=rb; i2b=rb; i2c=rb; i2d=rb; }
  else if (grp == 1) { i1a=rb+4; i1b=rb+5; i1c=rb+4; i1d=rb+5; i2a=rb+0; i2b=rb+1; i2c=rb; i2d=rb; }
  else if (grp == 2) { i1a=rb+0; i1b=rb+1; i1c=rb+2; i1d=rb+2; i2a=rb+2; i2b=rb+3; i2c=rb+4; i2d=rb+5; }
  else               { i1a=rb+3; i1b=rb+4; i1c=rb+5; i1d=rb+5; i2a=rb; i2b=rb; i2c=rb; i2d=rb; }

  // ---- state ----
  f32x4 h1s = splat(0.f), h2s = splat(0.f);
  fh2 z2 = (fh2){(__fp16)0.f, (__fp16)0.f};
  fh2 h2rd0 = z2, h2rd1 = z2, h2rd2 = z2, h2rd3 = z2;
  fh2 h1rd0 = z2, h1rd1 = z2, h1rd2 = z2;

  const float* xb = x;
  if (grp == 0)      xb = x + (size_t)(b0 + n) * Tlen * IND;
  else if (grp == 1) xb = x + (size_t)(b0 + n) * Tlen * IND + 8;
  else if (grp == 2) xb = x + (size_t)(b0 + n) * Tlen * IND + 16;
  v4f xr0 = {0,0,0,0}, xr1 = {0,0,0,0};
  v2f xr2 = {0,0};
  if (grp <= 1)      { xr0 = *(const v4f*)xb; xr1 = *(const v4f*)(xb + 4); }
  else if (grp == 2) { xr2 = *(const v2f*)xb; }
  fh8 af0;   // L0 A-operand for step t: nominal k = [x(0..17) | h1(18..29) | pad]
  if (grp <= 1)      af0 = mk8(pk(xr0.x, xr0.y), pk(xr0.z, xr0.w), pk(xr1.x, xr1.y), pk(xr1.z, xr1.w));
  else if (grp == 2) af0 = mk8(pk(xr2.x, xr2.y), z2, z2, z2);    // h1_{-1} = 0
  else               af0 = mk8(z2, z2, z2, z2);

  for (int t = 0; t < Tlen; ++t) {
    if (t + 1 < Tlen) {   // prefetch x[t+1]
      const float* p = xb + (size_t)(t + 1) * IND;
      if (grp <= 1)      { xr0 = *(const v4f*)p; xr1 = *(const v4f*)(p + 4); }
      else if (grp == 2) { xr2 = *(const v2f*)p; }
    }
    // ---- layer 0 ----
    f32x4 A0 = MFMA(af0, w0[0], cb00);
    f32x4 A1 = MFMA(af0, w0[1], cb01);
    f32x4 A2 = MFMA(af0, w0[2], cb02);
    f32x4 A3 = MFMA(af0, w0[3], cb03);
#pragma unroll
    for (int i = 0; i < 4; ++i) {
      float r = sigmoid_s(A0[i]), zg = sigmoid_s(A1[i]);
      float nn = tanh_s(A2[i] + r * A3[i]);
      h1s[i] = nn + zg * (h1s[i] - nn);
    }
#pragma unroll
    for (int i = 0; i < 4; ++i)
      if (wrok[i]) ((fp16a*)h1w)[wr_idx[i]] = (__fp16)h1s[i];
    h1rd0 = ldsrd(h1w, i1a); h1rd1 = ldsrd(h1w, i1b); h1rd2 = ldsrd(h1w, i1c);
    fh2 h1rd3 = ldsrd(h1w, i1d);
    // ---- layer 1: A nominal k = [h1(0..11) | h2(12..23) | pad] ----
    fh8 af1;
    if (grp == 0)      af1 = mk8(h1rd0, h1rd1, h1rd2, h1rd3);
    else if (grp == 1) af1 = mk8(h1rd0, h1rd1, h2rd0, h2rd1);
    else if (grp == 2) af1 = mk8(h2rd0, h2rd1, h2rd2, h2rd3);
    else               af1 = mk8(z2, z2, z2, z2);
    f32x4 B0 = MFMA(af1, w1[0], cb10);
    f32x4 B1 = MFMA(af1, w1[1], cb11);
    f32x4 B2 = MFMA(af1, w1[2], cb12);
    f32x4 B3 = MFMA(af1, w1[3], cb13);
    // deferred FC: probed col 12 of B0 = fcw . h2_{t-1} + fcb = out[t-1]
    if (t > 0) {
#pragma unroll
      for (int i = 0; i < 4; ++i)
        if (fcok[i]) outq[i][t - 1] = B0[i];
    }
#pragma unroll
    for (int i = 0; i < 4; ++i) {
      float r = sigmoid_s(B0[i]), zg = sigmoid_s(B1[i]);
      float nn = tanh_s(B2[i] + r * B3[i]);
      h2s[i] = nn + zg * (h2s[i] - nn);
    }
#pragma unroll
    for (int i = 0; i < 4; ++i)
      if (wrok[i]) ((fp16a*)h2w)[wr_idx[i]] = (__fp16)h2s[i];
    h2rd0 = ldsrd(h2w, i2a); h2rd1 = ldsrd(h2w, i2b);
    h2rd2 = ldsrd(h2w, i2c); h2rd3 = ldsrd(h2w, i2d);
    // ---- build L0 A-operand for t+1 ----
    if (grp <= 1)      af0 = mk8(pk(xr0.x, xr0.y), pk(xr0.z, xr0.w), pk(xr1.x, xr1.y), pk(xr1.z, xr1.w));
    else if (grp == 2) af0 = mk8(pk(xr2.x, xr2.y), h1rd0, h1rd1, h1rd2);
    else               af0 = mk8(h1rd0, h1rd1, h1rd2, z2);
  }
  // epilogue (layout-free): lane L handles batch L
  if (L < 16) {
    float o = fcb[0];
#pragma unroll
    for (int jj = 0; jj < HD; ++jj)
      o += (float)((const fp16a*)h2w)[L * 12 + jj] * fcw[jj];
    out[(size_t)(b0 + L) * Tlen + (Tlen - 1)] = o;
  }
}

extern "C" void kernel_launch(void* const* d_in, const int* in_sizes, int n_in,
                              void* d_out, int out_size, void* d_ws, size_t ws_size,
                              hipStream_t stream) {
  (void)in_sizes; (void)n_in; (void)d_ws; (void)ws_size; (void)out_size;
  const float* x    = (const float*)d_in[0];
  const float* wih0 = (const float*)d_in[1];
  const float* whh0 = (const float*)d_in[2];
  const float* bih0 = (const float*)d_in[3];
  const float* bhh0 = (const float*)d_in[4];
  const float* wih1 = (const float*)d_in[5];
  const float* whh1 = (const float*)d_in[6];
  const float* bih1 = (const float*)d_in[7];
  const float* bhh1 = (const float*)d_in[8];
  const float* fcw  = (const float*)d_in[9];
  const float* fcb  = (const float*)d_in[10];
  float* out = (float*)d_out;

  hipLaunchKernelGGL(gru2_mfma_p, dim3(4096 / 16), dim3(64), 0, stream,
                     x, wih0, whh0, bih0, bhh0, wih1, whh1, bih1, bhh1, fcw, fcb, out);
}

// Round 19
// 260.284 us; speedup vs baseline: 1.5955x; 1.5955x over previous
//
#include <hip/hip_runtime.h>

#define Bsz 4096
#define Tlen 512
#define IND 18
#define HD 12
#define L2E 1.44269504088896340736f

typedef float v2 __attribute__((ext_vector_type(2)));
typedef _Float16 h2t __attribute__((ext_vector_type(2)));
typedef _Float16 h4t __attribute__((ext_vector_type(4)));

#define HZERO ((h2t){(_Float16)0.f, (_Float16)0.f})

// v_pk_fma_f16: 32-bit packed op -> 2 f16 FMAs per 2-cycle wave issue (2x f32 rate)
__device__ __forceinline__ h2t pkh(h2t a, h2t b, h2t c) {
  return __builtin_elementwise_fma(a, b, c);
}
__device__ __forceinline__ float hsum(h2t a) { return (float)a[0] + (float)a[1]; }
__device__ __forceinline__ h2t cvt2h(float a, float b) {
  return __builtin_bit_cast(h2t, __builtin_amdgcn_cvt_pkrtz(a, b));  // v_cvt_pkrtz_f16_f32
}
// args pre-scaled: sigmoid arg by log2e, tanh arg by 2*log2e (folded into weights)
__device__ __forceinline__ float sigmoid_s(float x) {
  return __builtin_amdgcn_rcpf(1.f + __builtin_amdgcn_exp2f(-x));
}
__device__ __forceinline__ float tanh_s(float x) {
  return 1.f - 2.f * __builtin_amdgcn_rcpf(1.f + __builtin_amdgcn_exp2f(x));
}
__device__ __forceinline__ h2t mkw(float a, float b, float s) {
  return (h2t){(_Float16)(a * s), (_Float16)(b * s)};   // RNE weight rounding
}

// Round-11 producer/consumer pipeline (4 steps/tick, 129 barriers) with ALL
// dot products as v_pk_fma_f16 chains (f16 accumulate, <=15 deep; combined to
// f32 only at gate boundaries) — 2x the dot issue rate of v_pk_fma_f32.
// f16 inputs/weights (exp2-prescaled); h1/h2 flow through LDS as f16; gate
// tails in f32 (r16-validated machinery). 1024 blocks * 2 waves = 2 waves/SIMD.
extern "C" __global__ void __launch_bounds__(128, 2) gru2_pkh(
    const float* __restrict__ x,
    const float* __restrict__ wih0, const float* __restrict__ whh0,
    const float* __restrict__ bih0, const float* __restrict__ bhh0,
    const float* __restrict__ wih1, const float* __restrict__ whh1,
    const float* __restrict__ bih1, const float* __restrict__ bhh1,
    const float* __restrict__ fcw, const float* __restrict__ fcb,
    float* __restrict__ out)
{
  const int tid    = threadIdx.x;
  const int lane15 = tid & 15;
  const int g      = (tid >> 4) & 3;     // batch within block (0..3)
  const bool isA   = (tid >> 6) == 0;
  const int b      = blockIdx.x * 4 + g;
  const int j      = (lane15 < HD) ? lane15 : (HD - 1);

  __shared__ _Float16 h1buf[2][4][4][16];   // [parity][step][batch][row], f16
  __shared__ _Float16 h2buf[4][16];         // B-private broadcast slot, f16

#define BAR()                                           \
  do {                                                  \
    asm volatile("s_waitcnt lgkmcnt(0)" ::: "memory");  \
    __builtin_amdgcn_s_barrier();                       \
    asm volatile("" ::: "memory");                      \
  } while (0)

  if (isA) {
    // ---------------- A: layer 0, steps 4k..4k+3 per tick ----------------
    h2t wr2[9], wz2[9], wn2[9];          // ih0 rows j/12+j/24+j, k-pairs
#pragma unroll
    for (int i = 0; i < 9; ++i) {
      wr2[i] = mkw(wih0[(0*HD+j)*IND + 2*i], wih0[(0*HD+j)*IND + 2*i+1], L2E);
      wz2[i] = mkw(wih0[(1*HD+j)*IND + 2*i], wih0[(1*HD+j)*IND + 2*i+1], L2E);
      wn2[i] = mkw(wih0[(2*HD+j)*IND + 2*i], wih0[(2*HD+j)*IND + 2*i+1], 2*L2E);
    }
    h2t ur2[6], uz2[6], un2[6];          // hh0
#pragma unroll
    for (int i = 0; i < 6; ++i) {
      ur2[i] = mkw(whh0[(0*HD+j)*HD + 2*i], whh0[(0*HD+j)*HD + 2*i+1], L2E);
      uz2[i] = mkw(whh0[(1*HD+j)*HD + 2*i], whh0[(1*HD+j)*HD + 2*i+1], L2E);
      un2[i] = mkw(whh0[(2*HD+j)*HD + 2*i], whh0[(2*HD+j)*HD + 2*i+1], 2*L2E);
    }
    const float brS = (bih0[j] + bhh0[j]) * L2E;
    const float bzS = (bih0[HD+j] + bhh0[HD+j]) * L2E;
    const float biS = bih0[2*HD+j] * (2*L2E);
    const float bhS = bhh0[2*HD+j] * (2*L2E);

    h2t hv[6];                           // h1[t-1] row pairs (f16)
#pragma unroll
    for (int i = 0; i < 6; ++i) hv[i] = HZERO;
    float h1 = 0.f;

    const v2* xp2 = (const v2*)(x + (size_t)b * Tlen * IND);  // 9 v2 per step
    h2t xb0[9], xb1[9];                  // f16 x pairs
    h2t Pr, Pz, Pn;                      // x-projection accs (f16 pairs, 9-deep)

#define LOADCVT(XH, T)                                                        \
    { const v2* p_ = xp2 + (size_t)(T) * 9;                                   \
      _Pragma("unroll")                                                       \
      for (int i = 0; i < 9; ++i) {                                           \
        v2 t_ = p_[i];                                                        \
        XH[i] = cvt2h(t_.x, t_.y);                                            \
      } }

#define PROJ(XH)                                                              \
    do {                                                                      \
      Pr = HZERO; Pz = HZERO; Pn = HZERO;                                     \
      _Pragma("unroll")                                                       \
      for (int i = 0; i < 9; ++i) {                                           \
        Pr = pkh(XH[i], wr2[i], Pr);                                          \
        Pz = pkh(XH[i], wz2[i], Pz);                                          \
        Pn = pkh(XH[i], wn2[i], Pn);                                          \
      }                                                                       \
    } while (0)

    LOADCVT(xb0, 0);
    PROJ(xb0);         // P = proj(x[0])
    LOADCVT(xb1, 1);
    LOADCVT(xb0, 2);

// Entering ASTEP(T, XN): P = proj(x[T]); XN holds x[T+1]; other buf x[T+2].
#define ASTEP(T, XN)                                                          \
    do {                                                                      \
      h2t ra = Pr, za = Pz, ha = HZERO;   /* hh0 continues the proj chains */ \
      _Pragma("unroll")                                                       \
      for (int i = 0; i < 6; ++i) {                                           \
        ra = pkh(hv[i], ur2[i], ra);                                          \
        za = pkh(hv[i], uz2[i], za);                                          \
        ha = pkh(hv[i], un2[i], ha);                                          \
      }                                                                       \
      float ar = brS + hsum(ra), az = bzS + hsum(za);                         \
      float hn = bhS + hsum(ha), an = biS + hsum(Pn);                         \
      float r = sigmoid_s(ar), zg = sigmoid_s(az);                            \
      float n = tanh_s(an + r * hn);                                          \
      h1 = n + zg * (h1 - n);                                                 \
      _Float16* sp = &h1buf[k & 1][(T) & 3][g][0];                            \
      sp[lane15] = (_Float16)h1;  /* slots 12-15 clamped dup, never read */   \
      h4t q0 = ((const h4t*)sp)[0];   /* readback right after write */        \
      h4t q1 = ((const h4t*)sp)[1];                                           \
      h4t q2 = ((const h4t*)sp)[2];                                           \
      PROJ(XN);   /* next-step projections cover the ds_read latency */       \
      if ((T) + 3 < Tlen) LOADCVT(XN, (T) + 3);                               \
      hv[0] = (h2t){q0[0], q0[1]}; hv[1] = (h2t){q0[2], q0[3]};               \
      hv[2] = (h2t){q1[0], q1[1]}; hv[3] = (h2t){q1[2], q1[3]};               \
      hv[4] = (h2t){q2[0], q2[1]}; hv[5] = (h2t){q2[2], q2[3]};               \
    } while (0)

    for (int k = 0; k < 129; ++k) {
      if (k < 128) {
        const int t0 = 4 * k;
        ASTEP(t0 + 0, xb1);
        ASTEP(t0 + 1, xb0);
        ASTEP(t0 + 2, xb1);
        ASTEP(t0 + 3, xb0);
      }
      BAR();
    }
#undef ASTEP
#undef PROJ
#undef LOADCVT
  } else {
    // ---------------- B: layer 1 + FC, steps 4(k-1)..4(k-1)+3 ----------------
    h2t vr2[6], vz2[6], vn2[6];          // ih1
    h2t sr2[6], sz2[6], sn2[6];          // hh1
    h2t fw2[6];                          // fc (unscaled)
#pragma unroll
    for (int i = 0; i < 6; ++i) {
      vr2[i] = mkw(wih1[(0*HD+j)*HD + 2*i], wih1[(0*HD+j)*HD + 2*i+1], L2E);
      vz2[i] = mkw(wih1[(1*HD+j)*HD + 2*i], wih1[(1*HD+j)*HD + 2*i+1], L2E);
      vn2[i] = mkw(wih1[(2*HD+j)*HD + 2*i], wih1[(2*HD+j)*HD + 2*i+1], 2*L2E);
      sr2[i] = mkw(whh1[(0*HD+j)*HD + 2*i], whh1[(0*HD+j)*HD + 2*i+1], L2E);
      sz2[i] = mkw(whh1[(1*HD+j)*HD + 2*i], whh1[(1*HD+j)*HD + 2*i+1], L2E);
      sn2[i] = mkw(whh1[(2*HD+j)*HD + 2*i], whh1[(2*HD+j)*HD + 2*i+1], 2*L2E);
      fw2[i] = mkw(fcw[2*i], fcw[2*i+1], 1.f);
    }
    const float br1S = (bih1[j] + bhh1[j]) * L2E;
    const float bz1S = (bih1[HD+j] + bhh1[HD+j]) * L2E;
    const float bi1S = bih1[2*HD+j] * (2*L2E);
    const float bh1S = bhh1[2*HD+j] * (2*L2E);
    const float fb   = fcb[0];

    h2t hw[6];                           // h2[t-1] row pairs (f16)
#pragma unroll
    for (int i = 0; i < 6; ++i) hw[i] = HZERO;
    float h2 = 0.f;
    float* outp = out + (size_t)b * Tlen;
    _Float16* sq = &h2buf[g][0];

#define READQ(Q, SIDX)                                                        \
    { const _Float16* sp_ = &h1buf[par][SIDX][g][0];                          \
      Q##0 = ((const h4t*)sp_)[0];                                            \
      Q##1 = ((const h4t*)sp_)[1];                                            \
      Q##2 = ((const h4t*)sp_)[2]; }

#define IH1(Q, ra, za, ia)                                                    \
    { h2t p0 = (h2t){Q##0[0], Q##0[1]}, p1 = (h2t){Q##0[2], Q##0[3]};         \
      h2t p2 = (h2t){Q##1[0], Q##1[1]}, p3 = (h2t){Q##1[2], Q##1[3]};         \
      h2t p4 = (h2t){Q##2[0], Q##2[1]}, p5 = (h2t){Q##2[2], Q##2[3]};         \
      ra = pkh(p0, vr2[0], ra); za = pkh(p0, vz2[0], za); ia = pkh(p0, vn2[0], ia); \
      ra = pkh(p1, vr2[1], ra); za = pkh(p1, vz2[1], za); ia = pkh(p1, vn2[1], ia); \
      ra = pkh(p2, vr2[2], ra); za = pkh(p2, vz2[2], za); ia = pkh(p2, vn2[2], ia); \
      ra = pkh(p3, vr2[3], ra); za = pkh(p3, vz2[3], za); ia = pkh(p3, vn2[3], ia); \
      ra = pkh(p4, vr2[4], ra); za = pkh(p4, vz2[4], za); ia = pkh(p4, vn2[4], ia); \
      ra = pkh(p5, vr2[5], ra); za = pkh(p5, vz2[5], za); ia = pkh(p5, vn2[5], ia); }

#define HH1FC(ra, za, ha, oa)                                                 \
    _Pragma("unroll")                                                         \
    for (int i = 0; i < 6; ++i) {                                             \
      ra = pkh(hw[i], sr2[i], ra); za = pkh(hw[i], sz2[i], za);               \
      ha = pkh(hw[i], sn2[i], ha); oa = pkh(hw[i], fw2[i], oa);               \
    }

#define BTAIL(ra, za, ha, ia)                                                 \
    { float ar_ = br1S + hsum(ra), az_ = bz1S + hsum(za);                     \
      float hn_ = bh1S + hsum(ha), an_ = bi1S + hsum(ia);                     \
      float r_ = sigmoid_s(ar_), zg_ = sigmoid_s(az_);                        \
      float n_ = tanh_s(an_ + r_ * hn_);                                      \
      h2 = n_ + zg_ * (h2 - n_);                                              \
      sq[lane15] = (_Float16)h2;                                              \
      h4t c0 = ((const h4t*)sq)[0];                                           \
      h4t c1 = ((const h4t*)sq)[1];                                           \
      h4t c2 = ((const h4t*)sq)[2];                                           \
      hw[0] = (h2t){c0[0], c0[1]}; hw[1] = (h2t){c0[2], c0[3]};               \
      hw[2] = (h2t){c1[0], c1[1]}; hw[3] = (h2t){c1[2], c1[3]};               \
      hw[4] = (h2t){c2[0], c2[1]}; hw[5] = (h2t){c2[2], c2[3]}; }

// steady-state step: ih1 first (covers prev h2 readback), then hh1+FC
#define BSTEP(Q, OVAR)                                                        \
    { h2t ra = HZERO, za = HZERO, ia = HZERO;                                 \
      IH1(Q, ra, za, ia)                                                      \
      h2t ha = HZERO, oa = HZERO;                                             \
      HH1FC(ra, za, ha, oa)                                                   \
      OVAR = fb + hsum(oa);                                                   \
      BTAIL(ra, za, ha, ia) }

    for (int k = 0; k < 129; ++k) {
      if (k >= 1) {
        const int par = (k - 1) & 1;
        const int s0 = 4 * (k - 1);
        h4t qa0, qa1, qa2, qb0, qb1, qb2;
        READQ(qa, 0)
        READQ(qb, 1)
        float o0, o1, o2, o3;
        { // S=0: hh1+FC first (hw landed a barrier ago) -> covers qa reads
          h2t ra = HZERO, za = HZERO, ha = HZERO, oa = HZERO;
          HH1FC(ra, za, ha, oa)
          o0 = fb + hsum(oa);
          h2t ia = HZERO;
          IH1(qa, ra, za, ia)
          BTAIL(ra, za, ha, ia)
        }
        READQ(qa, 2)   // prefetch h1 for S=2
        BSTEP(qb, o1)
        READQ(qb, 3)   // prefetch h1 for S=3
        BSTEP(qa, o2)
        BSTEP(qb, o3)
        if (lane15 == 0) {   // one exec toggle per tick
          if (k >= 2) outp[s0 - 1] = o0;
          outp[s0] = o1; outp[s0 + 1] = o2; outp[s0 + 2] = o3;
        }
      }
      BAR();
    }
#undef READQ
#undef IH1
#undef HH1FC
#undef BTAIL
#undef BSTEP
    // epilogue: FC on h2[Tlen-1]
    h2t oa = HZERO;
#pragma unroll
    for (int i = 0; i < 6; ++i) oa = pkh(hw[i], fw2[i], oa);
    if (lane15 == 0) outp[Tlen - 1] = fb + hsum(oa);
  }
#undef BAR
}

extern "C" void kernel_launch(void* const* d_in, const int* in_sizes, int n_in,
                              void* d_out, int out_size, void* d_ws, size_t ws_size,
                              hipStream_t stream) {
  (void)in_sizes; (void)n_in; (void)d_ws; (void)ws_size; (void)out_size;
  const float* x    = (const float*)d_in[0];
  const float* wih0 = (const float*)d_in[1];
  const float* whh0 = (const float*)d_in[2];
  const float* bih0 = (const float*)d_in[3];
  const float* bhh0 = (const float*)d_in[4];
  const float* wih1 = (const float*)d_in[5];
  const float* whh1 = (const float*)d_in[6];
  const float* bih1 = (const float*)d_in[7];
  const float* bhh1 = (const float*)d_in[8];
  const float* fcw  = (const float*)d_in[9];
  const float* fcb  = (const float*)d_in[10];
  float* out = (float*)d_out;

  hipLaunchKernelGGL(gru2_pkh, dim3(Bsz / 4), dim3(128), 0, stream,
                     x, wih0, whh0, bih0, bhh0, wih1, whh1, bih1, bhh1, fcw, fcb, out);
}